// Round 1
// baseline (909.321 us; speedup 1.0000x reference)
//
#include <hip/hip_runtime.h>
#include <stdint.h>

#define DIN 128
#define SOUT 128
#define NB 8
#define MM 16
#define M2 256
#define M3 4096
#define M4 65536

typedef __attribute__((ext_vector_type(8))) short short8;
typedef __attribute__((ext_vector_type(4))) float floatx4;

__device__ __forceinline__ uint16_t f2bf(float f) {
  union { float f; uint32_t u; } v; v.f = f;
  uint32_t u = v.u;
  return (uint16_t)((u + 0x7FFFu + ((u >> 16) & 1u)) >> 16);
}
__device__ __forceinline__ float bf2f(uint16_t u) {
  union { uint32_t u; float f; } v; v.u = ((uint32_t)u) << 16;
  return v.f;
}

// ---------------------------------------------------------------------------
// K0: repack coefs (d,s,69) fp32 -> transposed bf16 weight matrices [s][k]
//   Wt4[s][d]            = coefs[d][s][0]
//   Wt3[B][s][a*128+d]   = coefs[d][s][1  + a*4 + B]   (B over 3-subsets)
//   Wt2[B][s][a*128+d]   = coefs[d][s][17 + a*6 + B]   (B over 2-subsets)
//   Wt1[B][s][a*128+d]   = coefs[d][s][53 + a*4 + B]   (B over 1-subsets)
// ---------------------------------------------------------------------------
__global__ void k0_prep(const float* __restrict__ coefs,
                        uint16_t* __restrict__ Wt4, uint16_t* __restrict__ Wt3,
                        uint16_t* __restrict__ Wt2, uint16_t* __restrict__ Wt1) {
  int idx = blockIdx.x * 256 + threadIdx.x;
  int b, d, s; uint16_t* dst;
  if (idx < 16384) {
    s = idx >> 7; d = idx & 127; b = 0; dst = Wt4 + idx;
  } else if (idx < 16384 + 262144) {
    int r = idx - 16384; int B = r >> 16; int r2 = r & 65535;
    s = r2 >> 9; int k = r2 & 511; int a = k >> 7; d = k & 127;
    b = 1 + a * 4 + B; dst = Wt3 + r;
  } else if (idx < 16384 + 262144 + 589824) {
    int r = idx - (16384 + 262144); int B = r / 98304; int r2 = r - B * 98304;
    s = r2 / 768; int k = r2 - s * 768; int a = k >> 7; d = k & 127;
    b = 17 + a * 6 + B; dst = Wt2 + r;
  } else if (idx < 16384 + 262144 + 589824 + 262144) {
    int r = idx - (16384 + 262144 + 589824); int B = r >> 16; int r2 = r & 65535;
    s = r2 >> 9; int k = r2 & 511; int a = k >> 7; d = k & 127;
    b = 53 + a * 4 + B; dst = Wt1 + r;
  } else {
    return;
  }
  *dst = f2bf(coefs[(d * 128 + s) * 69 + b]);
}

// ---------------------------------------------------------------------------
// K1: hierarchical pooling. One block per (n,d). Produces bf16:
//  Psing[a][n][d][4096]  (sum over set-axis a, kept axes ascending)
//  Ppair[p][n][d][256]   p in order (01,02,03,12,13,23)
//  Ptrip[q][n][d][16]    q in order (012,013,023,123)
// ---------------------------------------------------------------------------
__global__ __launch_bounds__(256) void k1_pool(
    const float* __restrict__ x,
    uint16_t* __restrict__ Psing, uint16_t* __restrict__ Ppair,
    uint16_t* __restrict__ Ptrip) {
  __shared__ float slab[256 * 17];  // i0-slab, rows (i1,i2) padded +1
  __shared__ float A1l[4096];       // [i0][(i2,i3)]  = sum over i1
  __shared__ float A2l[4096];       // [i0][(i1,i3)]  = sum over i2
  __shared__ float A3l[4096];       // [i0][(i1,i2)]  = sum over i3
  const int t = threadIdx.x;
  const int nd = blockIdx.x;  // n*128 + d
  const float* xp = x + (size_t)nd * M4;

  float a0[16];
#pragma unroll
  for (int j = 0; j < 16; ++j) a0[j] = 0.f;

  const int hi = t >> 4, lo = t & 15;
  for (int i0 = 0; i0 < 16; ++i0) {
    const float* rp = xp + i0 * 4096 + t * 16;  // thread owns row (i1,i2)=t
    float r[16];
#pragma unroll
    for (int q = 0; q < 4; ++q) {
      float4 v = *(const float4*)(rp + 4 * q);
      r[4 * q + 0] = v.x; r[4 * q + 1] = v.y; r[4 * q + 2] = v.z; r[4 * q + 3] = v.w;
    }
    float rs = 0.f;
#pragma unroll
    for (int j = 0; j < 16; ++j) {
      slab[t * 17 + j] = r[j];
      a0[j] += r[j];
      rs += r[j];
    }
    A3l[i0 * 256 + t] = rs;
    __syncthreads();
    float s1 = 0.f, s2 = 0.f;
#pragma unroll
    for (int ii = 0; ii < 16; ++ii) {
      s1 += slab[(ii * 16 + hi) * 17 + lo];  // sum over i1: (i2,i3)=(hi,lo)
      s2 += slab[(hi * 16 + ii) * 17 + lo];  // sum over i2: (i1,i3)=(hi,lo)
    }
    A1l[i0 * 256 + t] = s1;
    A2l[i0 * 256 + t] = s2;
    __syncthreads();
  }

  // Psing[0] from registers (kept (i1,i2,i3), v = t*16+j)
  {
    size_t base = (size_t)nd * M3;
#pragma unroll
    for (int j = 0; j < 8; ++j) {
      uint32_t w = (uint32_t)f2bf(a0[2 * j]) | ((uint32_t)f2bf(a0[2 * j + 1]) << 16);
      *(uint32_t*)(Psing + base + t * 16 + 2 * j) = w;
    }
  }
  // Psing[1..3]: linear layouts already match (i0 major)
  for (int a = 1; a <= 3; ++a) {
    const float* src = (a == 1) ? A1l : (a == 2) ? A2l : A3l;
    size_t base = ((size_t)a * 1024 + nd) * M3;
    for (int it = 0; it < 8; ++it) {
      int idx = it * 512 + t * 2;
      float2 v = *(const float2*)(src + idx);
      uint32_t w = (uint32_t)f2bf(v.x) | ((uint32_t)f2bf(v.y) << 16);
      *(uint32_t*)(Psing + base + idx) = w;
    }
  }
  // pairs (thread t owns one element of each, coords (hi,lo))
  float p[6];
#pragma unroll
  for (int i = 0; i < 6; ++i) p[i] = 0.f;
#pragma unroll
  for (int ii = 0; ii < 16; ++ii) {
    p[0] += A1l[ii * 256 + t];                // P01 kept (i2,i3)=(hi,lo)
    p[1] += A2l[ii * 256 + t];                // P02 kept (i1,i3)
    p[2] += A3l[ii * 256 + t];                // P03 kept (i1,i2)
    p[3] += A1l[hi * 256 + ii * 16 + lo];     // P12 kept (i0,i3), sum i2
    p[4] += A3l[hi * 256 + ii * 16 + lo];     // P13 kept (i0,i2), sum i1
    p[5] += A2l[hi * 256 + lo * 16 + ii];     // P23 kept (i0,i1), sum i3
  }
  float* pairbuf = slab;  // overlay (slab dead)
  for (int pi = 0; pi < 6; ++pi) {
    pairbuf[pi * 256 + t] = p[pi];
    Ppair[((size_t)pi * 1024 + nd) * M2 + t] = f2bf(p[pi]);
  }
  __syncthreads();
  if (t < 16) {
    float t0 = 0, t1 = 0, t2 = 0, t3 = 0;
#pragma unroll
    for (int ii = 0; ii < 16; ++ii) {
      t0 += pairbuf[0 * 256 + ii * 16 + t];  // P012[i3] = sum_i2 P01
      t1 += pairbuf[0 * 256 + t * 16 + ii];  // P013[i2] = sum_i3 P01
      t2 += pairbuf[1 * 256 + t * 16 + ii];  // P023[i1] = sum_i3 P02
      t3 += pairbuf[3 * 256 + t * 16 + ii];  // P123[i0] = sum_i3 P12
    }
    Ptrip[((size_t)0 * 1024 + nd) * 16 + t] = f2bf(t0);
    Ptrip[((size_t)1 * 1024 + nd) * 16 + t] = f2bf(t1);
    Ptrip[((size_t)2 * 1024 + nd) * 16 + t] = f2bf(t2);
    Ptrip[((size_t)3 * 1024 + nd) * 16 + t] = f2bf(t3);
  }
}

// ---------------------------------------------------------------------------
// K2: grouped small matmuls, MFMA 16x16x32 bf16.
//   T3[B][n][s][4096] = sum_a Wt3[B][:, a*128+d] * Psing[a]
//   T2[B][n][s][256], T1[B][n][s][16] analogous.
// Block: C[s=128][v=64], K staged in 128-chunks (1 chunk per source pool).
// ---------------------------------------------------------------------------
__global__ __launch_bounds__(256) void k2_small(
    const uint16_t* __restrict__ Psing, const uint16_t* __restrict__ Ppair,
    const uint16_t* __restrict__ Ptrip, const uint16_t* __restrict__ Wt3,
    const uint16_t* __restrict__ Wt2, const uint16_t* __restrict__ Wt1,
    uint16_t* __restrict__ T3, uint16_t* __restrict__ T2,
    uint16_t* __restrict__ T1) {
  __shared__ __align__(16) uint16_t Alds[128 * 136];
  __shared__ __align__(16) uint16_t Blds[64 * 136];
  const int t = threadIdx.x;
  int bid = blockIdx.x;
  const uint16_t *W, *P;
  uint16_t* dst;
  int n, vt, cols, K, chunks;
  if (bid < 2048) {
    int B = bid >> 9, r = bid & 511; n = r >> 6; vt = r & 63;
    cols = 4096; K = 512; chunks = 4;
    W = Wt3 + (size_t)B * 128 * 512; P = Psing;
    dst = T3 + (size_t)(B * 8 + n) * 128 * 4096;
  } else if (bid < 2240) {
    int g = bid - 2048; int B = g >> 5, r = g & 31; n = r >> 2; vt = r & 3;
    cols = 256; K = 768; chunks = 6;
    W = Wt2 + (size_t)B * 128 * 768; P = Ppair;
    dst = T2 + (size_t)(B * 8 + n) * 128 * 256;
  } else {
    int g = bid - 2240; int B = g >> 3; n = g & 7; vt = 0;
    cols = 16; K = 512; chunks = 4;
    W = Wt1 + (size_t)B * 128 * 512; P = Ptrip;
    dst = T1 + (size_t)(B * 8 + n) * 128 * 16;
  }
  const int lane = t & 63, wave = t >> 6;
  const int quad = lane >> 4, l15 = lane & 15;
  const int vbase = vt * 64;
  floatx4 acc[2][4];
#pragma unroll
  for (int i = 0; i < 2; ++i)
#pragma unroll
    for (int j = 0; j < 4; ++j) acc[i][j] = (floatx4){0.f, 0.f, 0.f, 0.f};

  for (int c = 0; c < chunks; ++c) {
    {  // stage A: W[s][c*128 .. +128] -> Alds[s][k]
      const uint32_t* Wp = (const uint32_t*)W;
      int Kh = K >> 1;
#pragma unroll
      for (int it = 0; it < 32; ++it) {
        int u = it * 256 + t;
        int s = u >> 6, kk = u & 63;
        *(uint32_t*)(Alds + s * 136 + kk * 2) = Wp[s * Kh + c * 64 + kk];
      }
    }
    {  // stage B transposed: Blds[v][k=d], pool c
      const uint16_t* src = P + ((size_t)c * 8 + n) * 128 * cols;
      if (cols >= 64) {
#pragma unroll
        for (int it = 0; it < 8; ++it) {
          int u = it * 256 + t;
          int vp = u & 31, dp = u >> 5;
          int v = vp * 2, d = dp * 2;
          uint32_t lo2 = *(const uint32_t*)(src + (size_t)d * cols + vbase + v);
          uint32_t hi2 = *(const uint32_t*)(src + (size_t)(d + 1) * cols + vbase + v);
          *(uint32_t*)(Blds + v * 136 + d) = (lo2 & 0xFFFFu) | (hi2 << 16);
          *(uint32_t*)(Blds + (v + 1) * 136 + d) = (lo2 >> 16) | (hi2 & 0xFFFF0000u);
        }
      } else {
        for (int it = 0; it < 8; ++it) {
          int u = it * 256 + t;
          int vp = u & 31, dp = u >> 5;
          int v = vp * 2, d = dp * 2;
          int v0 = (v < cols) ? v : 0, v1 = (v + 1 < cols) ? v + 1 : 0;
          uint16_t a00 = src[(size_t)d * cols + v0], a01 = src[(size_t)d * cols + v1];
          uint16_t a10 = src[(size_t)(d + 1) * cols + v0], a11 = src[(size_t)(d + 1) * cols + v1];
          *(uint32_t*)(Blds + v * 136 + d) = (uint32_t)a00 | ((uint32_t)a10 << 16);
          *(uint32_t*)(Blds + (v + 1) * 136 + d) = (uint32_t)a01 | ((uint32_t)a11 << 16);
        }
      }
    }
    __syncthreads();
#pragma unroll
    for (int ks = 0; ks < 4; ++ks) {
      int kb = ks * 32 + 8 * quad;
      short8 af[2], bfr[4];
#pragma unroll
      for (int i = 0; i < 2; ++i)
        af[i] = *(const short8*)(Alds + ((wave * 2 + i) * 16 + l15) * 136 + kb);
#pragma unroll
      for (int j = 0; j < 4; ++j)
        bfr[j] = *(const short8*)(Blds + (j * 16 + l15) * 136 + kb);
#pragma unroll
      for (int i = 0; i < 2; ++i)
#pragma unroll
        for (int j = 0; j < 4; ++j)
          acc[i][j] = __builtin_amdgcn_mfma_f32_16x16x32_bf16(af[i], bfr[j], acc[i][j], 0, 0, 0);
    }
    __syncthreads();
  }
#pragma unroll
  for (int i = 0; i < 2; ++i) {
#pragma unroll
    for (int j = 0; j < 4; ++j) {
      int vg = vbase + j * 16 + l15;
      if (vg < cols) {
#pragma unroll
        for (int rgi = 0; rgi < 4; ++rgi) {
          int s = (wave * 2 + i) * 16 + quad * 4 + rgi;
          dst[(size_t)s * cols + vg] = f2bf(acc[i][j][rgi]);
        }
      }
    }
  }
}

// ---------------------------------------------------------------------------
// K3: main fused pass. Per block: n fixed, (i0,i1) fixed, i2 in [i2b,i2b+4),
// i3 full. C[s=128][v=64] = Wt4 * x_tile (MFMA), epilogue adds the 14
// broadcast terms (grouped: per-(s,i2) table g2, per-(s,i3) table g3,
// 3 direct bf16 loads/element) + bias; writes out.
// ---------------------------------------------------------------------------
__global__ __launch_bounds__(256) void k3_main(
    const float* __restrict__ x, const float* __restrict__ bias,
    const uint16_t* __restrict__ Wt4, const uint16_t* __restrict__ T3,
    const uint16_t* __restrict__ T2, const uint16_t* __restrict__ T1,
    float* __restrict__ out) {
  __shared__ __align__(16) uint16_t Alds[128 * 136];
  __shared__ __align__(16) uint16_t Blds[64 * 136];
  const int t = threadIdx.x;
  const int bid = blockIdx.x;
  const int n = bid >> 10, vt = bid & 1023;
  const int v4base = vt * 64;
  const int i0 = vt >> 6, i1 = (vt >> 2) & 15, i2b = (vt & 3) * 4;
  const int lane = t & 63, wave = t >> 6, quad = lane >> 4, l15 = lane & 15;

  {  // stage A = Wt4 (128x128)
    const uint32_t* Wp = (const uint32_t*)Wt4;
#pragma unroll
    for (int it = 0; it < 32; ++it) {
      int u = it * 256 + t;
      int s = u >> 6, kk = u & 63;
      *(uint32_t*)(Alds + s * 136 + kk * 2) = Wp[s * 64 + kk];
    }
  }
  {  // stage B = x[n][d][v4base..+64] transposed to [v][d] bf16
    const float* xp = x + (size_t)n * 128 * M4 + v4base;
#pragma unroll
    for (int it = 0; it < 8; ++it) {
      int u = it * 256 + t;
      int vp = u & 31, dp = u >> 5;
      int v = vp * 2, d = dp * 2;
      float2 L0 = *(const float2*)(xp + (size_t)d * M4 + v);
      float2 L1 = *(const float2*)(xp + (size_t)(d + 1) * M4 + v);
      *(uint32_t*)(Blds + v * 136 + d) = (uint32_t)f2bf(L0.x) | ((uint32_t)f2bf(L1.x) << 16);
      *(uint32_t*)(Blds + (v + 1) * 136 + d) = (uint32_t)f2bf(L0.y) | ((uint32_t)f2bf(L1.y) << 16);
    }
  }
  floatx4 acc[2][4];
#pragma unroll
  for (int i = 0; i < 2; ++i)
#pragma unroll
    for (int j = 0; j < 4; ++j) acc[i][j] = (floatx4){0.f, 0.f, 0.f, 0.f};
  __syncthreads();
#pragma unroll
  for (int ks = 0; ks < 4; ++ks) {
    int kb = ks * 32 + 8 * quad;
    short8 af[2], bfr[4];
#pragma unroll
    for (int i = 0; i < 2; ++i)
      af[i] = *(const short8*)(Alds + ((wave * 2 + i) * 16 + l15) * 136 + kb);
#pragma unroll
    for (int j = 0; j < 4; ++j)
      bfr[j] = *(const short8*)(Blds + (j * 16 + l15) * 136 + kb);
#pragma unroll
    for (int i = 0; i < 2; ++i)
#pragma unroll
      for (int j = 0; j < 4; ++j)
        acc[i][j] = __builtin_amdgcn_mfma_f32_16x16x32_bf16(af[i], bfr[j], acc[i][j], 0, 0, 0);
  }
  __syncthreads();

  // build g2 (per s, per i2rel) and g3 (per s, per i3), overlaid on Blds
  float* g2 = (float*)Blds;        // 512 floats
  float* g3 = g2 + 512;            // 2048 floats (total 10240B <= 17408B)
  for (int e = t; e < 512; e += 256) {
    int s = e >> 2, r = e & 3, i2 = i2b + r;
    size_t r3 = (size_t)n * 128 + s;
    float val = bias[s]
      + bf2f(T3[(0 * 1024 + r3) * 4096 + (i0 * 16 + i1) * 16 + i2])  // T3_012
      + bf2f(T2[(1 * 1024 + r3) * 256 + i0 * 16 + i2])               // T2_02
      + bf2f(T2[(3 * 1024 + r3) * 256 + i1 * 16 + i2])               // T2_12
      + bf2f(T1[(2 * 1024 + r3) * 16 + i2])                          // T1_2
      + bf2f(T2[(0 * 1024 + r3) * 256 + i0 * 16 + i1])               // T2_01
      + bf2f(T1[(0 * 1024 + r3) * 16 + i0])                          // T1_0
      + bf2f(T1[(1 * 1024 + r3) * 16 + i1]);                         // T1_1
    g2[e] = val;
  }
  for (int e = t; e < 2048; e += 256) {
    int s = e >> 4, i3 = e & 15;
    size_t r3 = (size_t)n * 128 + s;
    float val =
        bf2f(T3[(1 * 1024 + r3) * 4096 + (i0 * 16 + i1) * 16 + i3])  // T3_013
      + bf2f(T2[(2 * 1024 + r3) * 256 + i0 * 16 + i3])               // T2_03
      + bf2f(T2[(4 * 1024 + r3) * 256 + i1 * 16 + i3])               // T2_13
      + bf2f(T1[(3 * 1024 + r3) * 16 + i3]);                         // T1_3
    g3[e] = val;
  }
  __syncthreads();

  const int i3 = l15;
#pragma unroll
  for (int i = 0; i < 2; ++i) {
#pragma unroll
    for (int rgi = 0; rgi < 4; ++rgi) {
      int s = (wave * 2 + i) * 16 + quad * 4 + rgi;
      size_t r3 = (size_t)n * 128 + s;
      const uint16_t* p023 = T3 + (2 * 1024 + r3) * 4096 + i0 * 256 + i3;
      const uint16_t* p123 = T3 + (3 * 1024 + r3) * 4096 + i1 * 256 + i3;
      const uint16_t* p23  = T2 + (5 * 1024 + r3) * 256 + i3;
      float g3v = g3[s * 16 + i3];
      float* op = out + r3 * M4 + v4base + i3;
#pragma unroll
      for (int j = 0; j < 4; ++j) {
        int i2 = i2b + j;
        float val = acc[i][j][rgi] + g2[s * 4 + j] + g3v
          + bf2f(p023[i2 * 16]) + bf2f(p123[i2 * 16]) + bf2f(p23[i2 * 16]);
        op[j * 16] = val;
      }
    }
  }
}

extern "C" void kernel_launch(void* const* d_in, const int* in_sizes, int n_in,
                              void* d_out, int out_size, void* d_ws, size_t ws_size,
                              hipStream_t stream) {
  const float* x = (const float*)d_in[0];
  const float* coefs = (const float*)d_in[1];
  const float* bias = (const float*)d_in[2];
  float* out = (float*)d_out;

  char* ws = (char*)d_ws;
  size_t off = 0;
  auto alloc = [&](size_t bytes) -> void* {
    size_t cur = (off + 255) & ~(size_t)255;
    off = cur + bytes;
    return (void*)(ws + cur);
  };
  uint16_t* Psing = (uint16_t*)alloc(4ull * 8 * 128 * 4096 * 2);
  uint16_t* Ppair = (uint16_t*)alloc(6ull * 8 * 128 * 256 * 2);
  uint16_t* Ptrip = (uint16_t*)alloc(4ull * 8 * 128 * 16 * 2);
  uint16_t* T3    = (uint16_t*)alloc(4ull * 8 * 128 * 4096 * 2);
  uint16_t* T2b   = (uint16_t*)alloc(6ull * 8 * 128 * 256 * 2);
  uint16_t* T1b   = (uint16_t*)alloc(4ull * 8 * 128 * 16 * 2);
  uint16_t* Wt4   = (uint16_t*)alloc(16384ull * 2);
  uint16_t* Wt3   = (uint16_t*)alloc(262144ull * 2);
  uint16_t* Wt2   = (uint16_t*)alloc(589824ull * 2);
  uint16_t* Wt1   = (uint16_t*)alloc(262144ull * 2);
  // total ~72.4 MiB of d_ws

  k0_prep<<<dim3(4416), dim3(256), 0, stream>>>(coefs, Wt4, Wt3, Wt2, Wt1);
  k1_pool<<<dim3(1024), dim3(256), 0, stream>>>(x, Psing, Ppair, Ptrip);
  k2_small<<<dim3(2272), dim3(256), 0, stream>>>(Psing, Ppair, Ptrip, Wt3, Wt2, Wt1,
                                                 T3, T2b, T1b);
  k3_main<<<dim3(8192), dim3(256), 0, stream>>>(x, bias, Wt4, T3, T2b, T1b, out);
}

// Round 2
// 663.566 us; speedup vs baseline: 1.3704x; 1.3704x over previous
//
#include <hip/hip_runtime.h>
#include <stdint.h>

#define DIN 128
#define SOUT 128
#define NB 8
#define MM 16
#define M2 256
#define M3 4096
#define M4 65536

typedef __attribute__((ext_vector_type(8))) short short8;
typedef __attribute__((ext_vector_type(4))) float floatx4;

__device__ __forceinline__ uint16_t f2bf(float f) {
  union { float f; uint32_t u; } v; v.f = f;
  uint32_t u = v.u;
  return (uint16_t)((u + 0x7FFFu + ((u >> 16) & 1u)) >> 16);
}
__device__ __forceinline__ float bf2f(uint16_t u) {
  union { uint32_t u; float f; } v; v.u = ((uint32_t)u) << 16;
  return v.f;
}

// async global->LDS DMA, 16B per lane. LDS dest = wave-uniform base + lane*16.
__device__ __forceinline__ void async_copy16(const uint16_t* g, uint16_t* l) {
  __builtin_amdgcn_global_load_lds(
      (const __attribute__((address_space(1))) uint32_t*)g,
      (__attribute__((address_space(3))) uint32_t*)l, 16, 0, 0);
}

// Swizzled LDS tile addressing: row stride 128 bf16 (256B = 16 chunks of 16B),
// logical k-chunk ch stored at slot ch ^ (row&7).  -> 2-way-max bank aliasing
// on MFMA b128 reads (free), and DMA-compatible (contiguous lane order).
__device__ __forceinline__ int fidx(int r, int kb) {  // kb multiple of 8
  return r * 128 + ((((kb >> 3) ^ (r & 7))) << 3);
}
// dword index for packed store of elements (v,d),(v,d+1), d even
__device__ __forceinline__ int didx(int v, int d) {
  return v * 64 + ((((d >> 3) ^ (v & 7))) << 2) + ((d & 7) >> 1);
}

// ---------------------------------------------------------------------------
// K0: repack coefs (d,s,69) fp32 -> bf16 weights. Coalesced reads (lane = b),
// scattered (non-stalling) stores.
//   Wt4[s*128+d]                      = coefs[d][s][0]
//   Wt3[B][s*512 + a*128 + d]         = coefs[d][s][1  + a*4 + B]
//   Wt2[B][s*768 + a*128 + d]         = coefs[d][s][17 + a*6 + B]
//   Wt1[B][s*512 + a*128 + d]         = coefs[d][s][53 + a*4 + B]
// ---------------------------------------------------------------------------
__global__ void k0_prep(const float* __restrict__ coefs,
                        uint16_t* __restrict__ Wt4, uint16_t* __restrict__ Wt3,
                        uint16_t* __restrict__ Wt2, uint16_t* __restrict__ Wt1) {
  int g = blockIdx.x * 256 + threadIdx.x;  // [0, 16384*128)
  int row = g >> 7, j = g & 127;
  if (j >= 69) return;
  int d = row >> 7, s = row & 127;
  uint16_t h = f2bf(coefs[row * 69 + j]);
  int b = j;
  if (b == 0) {
    Wt4[s * 128 + d] = h;
  } else if (b < 17) {
    int i = b - 1; int B = i & 3, a = i >> 2;
    Wt3[B * 65536 + s * 512 + a * 128 + d] = h;
  } else if (b < 53) {
    int i = b - 17; int B = i % 6, a = i / 6;
    Wt2[B * 98304 + s * 768 + a * 128 + d] = h;
  } else {
    int i = b - 53; int B = i & 3, a = i >> 2;
    Wt1[B * 65536 + s * 512 + a * 128 + d] = h;
  }
}

// ---------------------------------------------------------------------------
// K1: hierarchical pooling, one block per (n,d). Register-prefetched x loads.
//  Psing[a][n][d][4096], Ppair[p][n][d][256], Ptrip[q][n][d][16]  (bf16)
// ---------------------------------------------------------------------------
__device__ __forceinline__ void load16(float* r, const float* p) {
#pragma unroll
  for (int q = 0; q < 4; ++q) {
    float4 v = *(const float4*)(p + 4 * q);
    r[4 * q + 0] = v.x; r[4 * q + 1] = v.y; r[4 * q + 2] = v.z; r[4 * q + 3] = v.w;
  }
}

__global__ __launch_bounds__(256) void k1_pool(
    const float* __restrict__ x,
    uint16_t* __restrict__ Psing, uint16_t* __restrict__ Ppair,
    uint16_t* __restrict__ Ptrip) {
  __shared__ float slab[256 * 17];  // i0-slab, rows (i1,i2), pad +1
  __shared__ float A1l[4096];       // [i0][(i2,i3)] = sum over i1
  __shared__ float A3l[4096];       // [i0][(i1,i2)] = sum over i3
  const int t = threadIdx.x;
  const int nd = blockIdx.x;  // n*128 + d
  const float* xp = x + (size_t)nd * M4;

  float a0[16];
#pragma unroll
  for (int j = 0; j < 16; ++j) a0[j] = 0.f;
  float p0 = 0.f, p1 = 0.f, p2 = 0.f;

  const int hi = t >> 4, lo = t & 15;
  float r[16];
  load16(r, xp + t * 16);  // i0 = 0
  for (int i0 = 0; i0 < 16; ++i0) {
    float rn[16];
    if (i0 < 15) load16(rn, xp + (i0 + 1) * 4096 + t * 16);  // prefetch
    float rs = 0.f;
#pragma unroll
    for (int j = 0; j < 16; ++j) {
      slab[t * 17 + j] = r[j];
      a0[j] += r[j];
      rs += r[j];
    }
    A3l[i0 * 256 + t] = rs;
    p2 += rs;
    __syncthreads();
    float s1 = 0.f, s2 = 0.f;
#pragma unroll
    for (int ii = 0; ii < 16; ++ii) {
      s1 += slab[(ii * 16 + hi) * 17 + lo];  // sum over i1: (i2,i3)=(hi,lo)
      s2 += slab[(hi * 16 + ii) * 17 + lo];  // sum over i2: (i1,i3)=(hi,lo)
    }
    A1l[i0 * 256 + t] = s1;
    p0 += s1;
    p1 += s2;
    // Psing[2] written incrementally (i0-major layout matches)
    Psing[((size_t)2 * 1024 + nd) * M3 + i0 * 256 + t] = f2bf(s2);
    __syncthreads();
#pragma unroll
    for (int j = 0; j < 16; ++j) r[j] = rn[j];
  }

  // Psing[0] from registers (kept (i1,i2,i3), v = t*16+j)
  {
    size_t base = (size_t)nd * M3;
#pragma unroll
    for (int j = 0; j < 8; ++j) {
      uint32_t w = (uint32_t)f2bf(a0[2 * j]) | ((uint32_t)f2bf(a0[2 * j + 1]) << 16);
      *(uint32_t*)(Psing + base + t * 16 + 2 * j) = w;
    }
  }
  // Psing[1] from A1l, Psing[3] from A3l (coalesced)
#pragma unroll
  for (int a = 1; a <= 3; a += 2) {
    const float* src = (a == 1) ? A1l : A3l;
    size_t base = ((size_t)a * 1024 + nd) * M3;
    for (int it = 0; it < 8; ++it) {
      int idx = it * 512 + t * 2;
      float2 v = *(const float2*)(src + idx);
      uint32_t w = (uint32_t)f2bf(v.x) | ((uint32_t)f2bf(v.y) << 16);
      *(uint32_t*)(Psing + base + idx) = w;
    }
  }
  // pairs: p0..p2 from register accumulation, p3..p5 from A1l/A3l
  float p3 = 0.f, p4 = 0.f, p5 = 0.f;
#pragma unroll
  for (int ii = 0; ii < 16; ++ii) {
    p3 += A1l[hi * 256 + ii * 16 + lo];   // P12 kept (i0,i3), sum i2
    p4 += A3l[hi * 256 + ii * 16 + lo];   // P13 kept (i0,i2), sum i1
    p5 += A3l[hi * 256 + lo * 16 + ii];   // P23 kept (i0,i1), sum i2 (== sum i2,i3)
  }
  float pv[6] = {p0, p1, p2, p3, p4, p5};
  float* pairbuf = slab;  // overlay (slab dead after last barrier)
#pragma unroll
  for (int pi = 0; pi < 6; ++pi) {
    pairbuf[pi * 256 + t] = pv[pi];
    Ppair[((size_t)pi * 1024 + nd) * M2 + t] = f2bf(pv[pi]);
  }
  __syncthreads();
  if (t < 16) {
    float t0 = 0, t1 = 0, t2 = 0, t3 = 0;
#pragma unroll
    for (int ii = 0; ii < 16; ++ii) {
      t0 += pairbuf[0 * 256 + ii * 16 + t];  // P012[i3]
      t1 += pairbuf[0 * 256 + t * 16 + ii];  // P013[i2]
      t2 += pairbuf[1 * 256 + t * 16 + ii];  // P023[i1]
      t3 += pairbuf[3 * 256 + t * 16 + ii];  // P123[i0]
    }
    Ptrip[((size_t)0 * 1024 + nd) * 16 + t] = f2bf(t0);
    Ptrip[((size_t)1 * 1024 + nd) * 16 + t] = f2bf(t1);
    Ptrip[((size_t)2 * 1024 + nd) * 16 + t] = f2bf(t2);
    Ptrip[((size_t)3 * 1024 + nd) * 16 + t] = f2bf(t3);
  }
}

// ---------------------------------------------------------------------------
// K2: grouped small matmuls, MFMA 16x16x32 bf16.
// A staged by async DMA (swizzled), B staged by batched loads + VALU repack.
// ---------------------------------------------------------------------------
__global__ __launch_bounds__(256) void k2_small(
    const uint16_t* __restrict__ Psing, const uint16_t* __restrict__ Ppair,
    const uint16_t* __restrict__ Ptrip, const uint16_t* __restrict__ Wt3,
    const uint16_t* __restrict__ Wt2, const uint16_t* __restrict__ Wt1,
    uint16_t* __restrict__ T3, uint16_t* __restrict__ T2,
    uint16_t* __restrict__ T1) {
  __shared__ __align__(16) uint16_t Alds[128 * 128];  // 32 KB
  __shared__ __align__(16) uint16_t Blds[64 * 128];   // 16 KB
  const int t = threadIdx.x;
  int bid = blockIdx.x;
  const uint16_t *W, *P;
  uint16_t* dst;
  int n, vt, cols, K, chunks;
  if (bid < 2048) {
    int B = bid >> 9, r = bid & 511; n = r >> 6; vt = r & 63;
    cols = 4096; K = 512; chunks = 4;
    W = Wt3 + (size_t)B * 128 * 512; P = Psing;
    dst = T3 + (size_t)(B * 8 + n) * 128 * 4096;
  } else if (bid < 2240) {
    int g = bid - 2048; int B = g >> 5, r = g & 31; n = r >> 2; vt = r & 3;
    cols = 256; K = 768; chunks = 6;
    W = Wt2 + (size_t)B * 128 * 768; P = Ppair;
    dst = T2 + (size_t)(B * 8 + n) * 128 * 256;
  } else {
    int g = bid - 2240; int B = g >> 3; n = g & 7; vt = 0;
    cols = 16; K = 512; chunks = 4;
    W = Wt1 + (size_t)B * 128 * 512; P = Ptrip;
    dst = T1 + (size_t)(B * 8 + n) * 128 * 16;
  }
  const int lane = t & 63, wave = t >> 6;
  const int quad = lane >> 4, l15 = lane & 15;
  const int vbase = vt * 64;
  const int dmarow = lane >> 4, dmaslot = lane & 15;
  floatx4 acc[2][4];
#pragma unroll
  for (int i = 0; i < 2; ++i)
#pragma unroll
    for (int j = 0; j < 4; ++j) acc[i][j] = (floatx4){0.f, 0.f, 0.f, 0.f};

  for (int c = 0; c < chunks; ++c) {
    // stage A via DMA: W[s][c*128 .. +128] -> Alds swizzled
#pragma unroll
    for (int i = 0; i < 8; ++i) {
      int win = wave * 8 + i;
      int rr = win * 4 + dmarow;                 // row s
      int cc = dmaslot ^ (rr & 7);               // source k-chunk
      async_copy16(W + (size_t)rr * K + c * 128 + cc * 8, Alds + win * 512);
    }
    // stage B transposed: Blds[v][k=d] swizzled, pool chunk c
    const uint16_t* src = P + ((size_t)c * 8 + n) * 128 * cols;
    if (cols >= 64) {
      uint32_t lo2[8], hi2[8];
#pragma unroll
      for (int it = 0; it < 8; ++it) {
        int u = it * 256 + t;
        int vp = u & 31, dp = u >> 5;
        int v = vp * 2, d = dp * 2;
        lo2[it] = *(const uint32_t*)(src + (size_t)d * cols + vbase + v);
        hi2[it] = *(const uint32_t*)(src + (size_t)(d + 1) * cols + vbase + v);
      }
#pragma unroll
      for (int it = 0; it < 8; ++it) {
        int u = it * 256 + t;
        int vp = u & 31, dp = u >> 5;
        int v = vp * 2, d = dp * 2;
        ((uint32_t*)Blds)[didx(v, d)] = (lo2[it] & 0xFFFFu) | (hi2[it] << 16);
        ((uint32_t*)Blds)[didx(v + 1, d)] = (lo2[it] >> 16) | (hi2[it] & 0xFFFF0000u);
      }
    } else {
      uint16_t a00[8], a01[8], a10[8], a11[8];
#pragma unroll
      for (int it = 0; it < 8; ++it) {
        int u = it * 256 + t;
        int vp = u & 31, dp = u >> 5;
        int v = vp * 2, d = dp * 2;
        int v0 = (v < 16) ? v : 0, v1 = (v + 1 < 16) ? v + 1 : 0;
        a00[it] = src[(size_t)d * cols + v0];
        a01[it] = src[(size_t)d * cols + v1];
        a10[it] = src[(size_t)(d + 1) * cols + v0];
        a11[it] = src[(size_t)(d + 1) * cols + v1];
      }
#pragma unroll
      for (int it = 0; it < 8; ++it) {
        int u = it * 256 + t;
        int vp = u & 31, dp = u >> 5;
        int v = vp * 2, d = dp * 2;
        ((uint32_t*)Blds)[didx(v, d)] = (uint32_t)a00[it] | ((uint32_t)a10[it] << 16);
        ((uint32_t*)Blds)[didx(v + 1, d)] = (uint32_t)a01[it] | ((uint32_t)a11[it] << 16);
      }
    }
    __syncthreads();
#pragma unroll
    for (int ks = 0; ks < 4; ++ks) {
      int kb = ks * 32 + 8 * quad;
      short8 af[2], bfr[4];
#pragma unroll
      for (int i = 0; i < 2; ++i)
        af[i] = *(const short8*)(Alds + fidx((wave * 2 + i) * 16 + l15, kb));
#pragma unroll
      for (int j = 0; j < 4; ++j)
        bfr[j] = *(const short8*)(Blds + fidx(j * 16 + l15, kb));
#pragma unroll
      for (int i = 0; i < 2; ++i)
#pragma unroll
        for (int j = 0; j < 4; ++j)
          acc[i][j] = __builtin_amdgcn_mfma_f32_16x16x32_bf16(af[i], bfr[j], acc[i][j], 0, 0, 0);
    }
    __syncthreads();
  }
#pragma unroll
  for (int i = 0; i < 2; ++i) {
#pragma unroll
    for (int j = 0; j < 4; ++j) {
      int vg = vbase + j * 16 + l15;
      if (vg < cols) {
#pragma unroll
        for (int rgi = 0; rgi < 4; ++rgi) {
          int s = (wave * 2 + i) * 16 + quad * 4 + rgi;
          dst[(size_t)s * cols + vg] = f2bf(acc[i][j][rgi]);
        }
      }
    }
  }
}

// ---------------------------------------------------------------------------
// K3: main fused pass. C[s=128][v=64] = Wt4 * x_tile via MFMA; epilogue adds
// 14 broadcast terms + bias; writes out.
// ---------------------------------------------------------------------------
__global__ __launch_bounds__(256) void k3_main(
    const float* __restrict__ x, const float* __restrict__ bias,
    const uint16_t* __restrict__ Wt4, const uint16_t* __restrict__ T3,
    const uint16_t* __restrict__ T2, const uint16_t* __restrict__ T1,
    float* __restrict__ out) {
  __shared__ __align__(16) uint16_t Alds[128 * 128];
  __shared__ __align__(16) uint16_t Blds[64 * 128];
  const int t = threadIdx.x;
  const int bid = blockIdx.x;
  const int n = bid >> 10, vt = bid & 1023;
  const int v4base = vt * 64;
  const int i0 = vt >> 6, i1 = (vt >> 2) & 15, i2b = (vt & 3) * 4;
  const int lane = t & 63, wave = t >> 6, quad = lane >> 4, l15 = lane & 15;
  const int dmarow = lane >> 4, dmaslot = lane & 15;

  // stage A = Wt4 (128x128) via DMA, swizzled
#pragma unroll
  for (int i = 0; i < 8; ++i) {
    int win = wave * 8 + i;
    int rr = win * 4 + dmarow;
    int cc = dmaslot ^ (rr & 7);
    async_copy16(Wt4 + rr * 128 + cc * 8, Alds + win * 512);
  }
  // stage B = x[n][d][v4base..+64] transposed to [v][d] bf16, swizzled
  {
    const float* xp = x + (size_t)n * 128 * M4 + v4base;
    float2 L0[8], L1[8];
#pragma unroll
    for (int it = 0; it < 8; ++it) {
      int u = it * 256 + t;
      int vp = u & 31, dp = u >> 5;
      int v = vp * 2, d = dp * 2;
      L0[it] = *(const float2*)(xp + (size_t)d * M4 + v);
      L1[it] = *(const float2*)(xp + (size_t)(d + 1) * M4 + v);
    }
#pragma unroll
    for (int it = 0; it < 8; ++it) {
      int u = it * 256 + t;
      int vp = u & 31, dp = u >> 5;
      int v = vp * 2, d = dp * 2;
      ((uint32_t*)Blds)[didx(v, d)] =
          (uint32_t)f2bf(L0[it].x) | ((uint32_t)f2bf(L1[it].x) << 16);
      ((uint32_t*)Blds)[didx(v + 1, d)] =
          (uint32_t)f2bf(L0[it].y) | ((uint32_t)f2bf(L1[it].y) << 16);
    }
  }
  floatx4 acc[2][4];
#pragma unroll
  for (int i = 0; i < 2; ++i)
#pragma unroll
    for (int j = 0; j < 4; ++j) acc[i][j] = (floatx4){0.f, 0.f, 0.f, 0.f};
  __syncthreads();
#pragma unroll
  for (int ks = 0; ks < 4; ++ks) {
    int kb = ks * 32 + 8 * quad;
    short8 af[2], bfr[4];
#pragma unroll
    for (int i = 0; i < 2; ++i)
      af[i] = *(const short8*)(Alds + fidx((wave * 2 + i) * 16 + l15, kb));
#pragma unroll
    for (int j = 0; j < 4; ++j)
      bfr[j] = *(const short8*)(Blds + fidx(j * 16 + l15, kb));
#pragma unroll
    for (int i = 0; i < 2; ++i)
#pragma unroll
      for (int j = 0; j < 4; ++j)
        acc[i][j] = __builtin_amdgcn_mfma_f32_16x16x32_bf16(af[i], bfr[j], acc[i][j], 0, 0, 0);
  }
  __syncthreads();

  // build g2 (per s, per i2rel) and g3 (per s, per i3), overlaid on Blds
  float* g2 = (float*)Blds;        // 512 floats
  float* g3 = g2 + 512;            // 2048 floats (10 KB <= 16 KB)
  for (int e = t; e < 512; e += 256) {
    int s = e >> 2, r = e & 3, i2 = i2b + r;
    size_t r3 = (size_t)n * 128 + s;
    float val = bias[s]
      + bf2f(T3[(0 * 1024 + r3) * 4096 + (i0 * 16 + i1) * 16 + i2])  // T3_012
      + bf2f(T2[(1 * 1024 + r3) * 256 + i0 * 16 + i2])               // T2_02
      + bf2f(T2[(3 * 1024 + r3) * 256 + i1 * 16 + i2])               // T2_12
      + bf2f(T1[(2 * 1024 + r3) * 16 + i2])                          // T1_2
      + bf2f(T2[(0 * 1024 + r3) * 256 + i0 * 16 + i1])               // T2_01
      + bf2f(T1[(0 * 1024 + r3) * 16 + i0])                          // T1_0
      + bf2f(T1[(1 * 1024 + r3) * 16 + i1]);                         // T1_1
    g2[e] = val;
  }
  for (int e = t; e < 2048; e += 256) {
    int s = e >> 4, i3 = e & 15;
    size_t r3 = (size_t)n * 128 + s;
    float val =
        bf2f(T3[(1 * 1024 + r3) * 4096 + (i0 * 16 + i1) * 16 + i3])  // T3_013
      + bf2f(T2[(2 * 1024 + r3) * 256 + i0 * 16 + i3])               // T2_03
      + bf2f(T2[(4 * 1024 + r3) * 256 + i1 * 16 + i3])               // T2_13
      + bf2f(T1[(3 * 1024 + r3) * 16 + i3]);                         // T1_3
    g3[e] = val;
  }
  __syncthreads();

  const int i3 = l15;
#pragma unroll
  for (int i = 0; i < 2; ++i) {
#pragma unroll
    for (int rgi = 0; rgi < 4; ++rgi) {
      int s = (wave * 2 + i) * 16 + quad * 4 + rgi;
      size_t r3 = (size_t)n * 128 + s;
      const uint16_t* p023 = T3 + (2 * 1024 + r3) * 4096 + i0 * 256 + i3;
      const uint16_t* p123 = T3 + (3 * 1024 + r3) * 4096 + i1 * 256 + i3;
      const uint16_t* p23  = T2 + (5 * 1024 + r3) * 256 + i3;
      uint16_t v023[4], v123[4], v23[4];
#pragma unroll
      for (int j = 0; j < 4; ++j) {
        int i2 = i2b + j;
        v023[j] = p023[i2 * 16];
        v123[j] = p123[i2 * 16];
        v23[j] = p23[i2 * 16];
      }
      float g3v = g3[s * 16 + i3];
      float* op = out + r3 * M4 + v4base + i3;
#pragma unroll
      for (int j = 0; j < 4; ++j) {
        float val = acc[i][j][rgi] + g2[s * 4 + j] + g3v
          + bf2f(v023[j]) + bf2f(v123[j]) + bf2f(v23[j]);
        op[j * 16] = val;
      }
    }
  }
}

extern "C" void kernel_launch(void* const* d_in, const int* in_sizes, int n_in,
                              void* d_out, int out_size, void* d_ws, size_t ws_size,
                              hipStream_t stream) {
  const float* x = (const float*)d_in[0];
  const float* coefs = (const float*)d_in[1];
  const float* bias = (const float*)d_in[2];
  float* out = (float*)d_out;

  char* ws = (char*)d_ws;
  size_t off = 0;
  auto alloc = [&](size_t bytes) -> void* {
    size_t cur = (off + 255) & ~(size_t)255;
    off = cur + bytes;
    return (void*)(ws + cur);
  };
  uint16_t* Psing = (uint16_t*)alloc(4ull * 8 * 128 * 4096 * 2);
  uint16_t* Ppair = (uint16_t*)alloc(6ull * 8 * 128 * 256 * 2);
  uint16_t* Ptrip = (uint16_t*)alloc(4ull * 8 * 128 * 16 * 2);
  uint16_t* T3    = (uint16_t*)alloc(4ull * 8 * 128 * 4096 * 2);
  uint16_t* T2b   = (uint16_t*)alloc(6ull * 8 * 128 * 256 * 2);
  uint16_t* T1b   = (uint16_t*)alloc(4ull * 8 * 128 * 16 * 2);
  uint16_t* Wt4   = (uint16_t*)alloc(16384ull * 2);
  uint16_t* Wt3   = (uint16_t*)alloc(262144ull * 2);
  uint16_t* Wt2   = (uint16_t*)alloc(589824ull * 2);
  uint16_t* Wt1   = (uint16_t*)alloc(262144ull * 2);
  // total ~72.4 MiB of d_ws

  k0_prep<<<dim3(8192), dim3(256), 0, stream>>>(coefs, Wt4, Wt3, Wt2, Wt1);
  k1_pool<<<dim3(1024), dim3(256), 0, stream>>>(x, Psing, Ppair, Ptrip);
  k2_small<<<dim3(2272), dim3(256), 0, stream>>>(Psing, Ppair, Ptrip, Wt3, Wt2, Wt1,
                                                 T3, T2b, T1b);
  k3_main<<<dim3(8192), dim3(256), 0, stream>>>(x, bias, Wt4, T3, T2b, T1b, out);
}